// Round 6
// baseline (505.732 us; speedup 1.0000x reference)
//
#include <hip/hip_runtime.h>
#include <math.h>

typedef __bf16 bf16_t;
typedef __bf16 bf16x8 __attribute__((ext_vector_type(8)));
typedef float  f32x4  __attribute__((ext_vector_type(4)));
typedef float  f32x16 __attribute__((ext_vector_type(16)));

#define B_    16
#define CIN_  32
#define COUT_ 32
#define G_    8
#define CH_   256      // Cin*Gin = K channels per tap
#define H_    64
#define W_    64
#define HID_  32
#define KS_   7
#define PAD_  3
#define WP_   70       // W + 2*PAD

// xp layout: [B][y(70)][c16(32)][x(70)][8ch]  (chunk-major rows).
#define ROW_ELEMS  (WP_ * CH_)                                // 17,920 per row
#define XP_ELEMS   ((size_t)B_ * WP_ * ROW_ELEMS)             // 20,070,400
#define XP_BYTES   (XP_ELEMS * 2)                             // 40,140,800

#define REPACK_BLOCKS (B_ * (H_ + 6))                         // 1120
#define GENW_BLOCKS   (G_ * G_)                               // 64
#define CONV_BLOCKS   (B_ * (H_ / 2))                         // 512 = 2/CU exactly

static __device__ __forceinline__ unsigned pack_bf16(float a, float b) {
    union { __bf16 h; unsigned short u; } ua, ub;
    ua.h = (__bf16)a; ub.h = (__bf16)b;
    return (unsigned)ua.u | ((unsigned)ub.u << 16);
}

static __device__ __forceinline__ void dma16(const bf16_t* g, bf16_t* l) {
    __builtin_amdgcn_global_load_lds(
        (const __attribute__((address_space(1))) void*)g,
        (__attribute__((address_space(3))) void*)l, 16, 0, 0);
}

// ---------------------------------------------------------------------------
// Fused prep — EXACT R0 version (empirically fastest; R1/R4 gen_w re-blocks
// both regressed ~70-100us).  repack blocks FIRST, gen_w LAST; gen_w block =
// (gout,gin) with W3 register reuse across all 49 taps.  Do NOT re-block
// gen_w again without isolating prep first.
__global__ void prep(const float* __restrict__ x, bf16_t* __restrict__ xp,
                     const float* __restrict__ thetas,
                     const float* __restrict__ W1, const float* __restrict__ b1,
                     const float* __restrict__ W2, const float* __restrict__ b2,
                     const float* __restrict__ W3, const float* __restrict__ b3,
                     bf16_t* __restrict__ w2out) {
    __shared__ float h1s[49][33];
    __shared__ float h2s[49][33];
    __shared__ float masks[49];
    int tid = threadIdx.x;
    if (blockIdx.x < REPACK_BLOCKS) {
        // ---------------- repack path ----------------
        int blk = blockIdx.x;
        int b = blk / (H_ + 6), hy = blk % (H_ + 6);
        const int4 z4 = make_int4(0, 0, 0, 0);
        if (hy >= H_) {
            int idx = hy - H_;
            int y = (idx < 3) ? idx : idx + 64;   // 0,1,2,67,68,69
            bf16_t* dst = xp + ((size_t)(b * WP_) + y) * ROW_ELEMS;
            for (int i = tid; i < ROW_ELEMS / 8; i += 256)
                *reinterpret_cast<int4*>(dst + (size_t)i * 8) = z4;
            return;
        }
        int lane = tid & 63, wv = tid >> 6;
        int r = lane >> 3;          // channel offset in tile -> w offset after T
        int t = lane & 7;           // w-chunk
        size_t orow = ((size_t)(b * WP_) + (hy + 3)) * ROW_ELEMS;
        for (int it = 0; it < 8; ++it) {
            int c0 = wv * 8 + it * 32;
            const float* src = x + ((size_t)(b * CH_ + c0 + r)) * (H_ * W_)
                                 + (size_t)hy * W_ + t * 8;
            float4 f0 = *reinterpret_cast<const float4*>(src);
            float4 f1 = *reinterpret_cast<const float4*>(src + 4);
            int d0 = (int)pack_bf16(f0.x, f0.y);
            int d1 = (int)pack_bf16(f0.z, f0.w);
            int d2 = (int)pack_bf16(f1.x, f1.y);
            int d3 = (int)pack_bf16(f1.z, f1.w);
            int p0, p1, p2, p3;
            p0 = __shfl_xor(d0, 32); p1 = __shfl_xor(d1, 32);
            p2 = __shfl_xor(d2, 32); p3 = __shfl_xor(d3, 32);
            if ((r & 4) == 0) { d2 = p0; d3 = p1; } else { d0 = p2; d1 = p3; }
            p0 = __shfl_xor(d0, 16); p1 = __shfl_xor(d1, 16);
            p2 = __shfl_xor(d2, 16); p3 = __shfl_xor(d3, 16);
            if ((r & 2) == 0) { d1 = p0; d3 = p2; } else { d0 = p1; d2 = p3; }
            p0 = __shfl_xor(d0, 8); p1 = __shfl_xor(d1, 8);
            p2 = __shfl_xor(d2, 8); p3 = __shfl_xor(d3, 8);
            if ((r & 1) == 0) {
                d0 = (d0 & 0xFFFF) | (p0 << 16);
                d1 = (d1 & 0xFFFF) | (p1 << 16);
                d2 = (d2 & 0xFFFF) | (p2 << 16);
                d3 = (d3 & 0xFFFF) | (p3 << 16);
            } else {
                d0 = (d0 & 0xFFFF0000) | ((unsigned)p0 >> 16);
                d1 = (d1 & 0xFFFF0000) | ((unsigned)p1 >> 16);
                d2 = (d2 & 0xFFFF0000) | ((unsigned)p2 >> 16);
                d3 = (d3 & 0xFFFF0000) | ((unsigned)p3 >> 16);
            }
            int xpos = t * 8 + r + 3;
            int c16 = c0 >> 3;
            int4 v = make_int4(d0, d1, d2, d3);
            // chunk-major: wave's 64 stores cover one contiguous 1024B run
            *reinterpret_cast<int4*>(xp + orow + ((size_t)c16 * WP_ + xpos) * 8) = v;
        }
        if (tid < 192) {   // zero w-border cols {0,1,2,67,68,69} in every chunk
            int col = tid >> 5, cg = tid & 31;
            int xx = (col < 3) ? col : col + 64;
            *reinterpret_cast<int4*>(xp + orow + ((size_t)cg * WP_ + xx) * 8) = z4;
        }
        return;
    }
    // ---------------- gen_w path: block = (gout, gin) ----------------
    int blk = blockIdx.x - REPACK_BLOCKS;
    int gin = blk & 7, gout = blk >> 3;
    const float TWO_PI = 6.283185307179586f;
    const float PI_F   = 3.14159265358979323846f;
    float th_o = thetas[gout], th_i = thetas[gin];
    float d = fmodf(th_i - th_o, TWO_PI);
    if (d < 0.0f) d += TWO_PI;
    float ag = d / PI_F - 1.0f;
    float ct = cosf(-th_o), st = sinf(-th_o);

    if (tid < 196) {
        int p = tid >> 2, q = tid & 3;       // tap, j-octet
        int ky = p / 7, kx = p % 7;
        float yy = (float)(ky - 3) / 3.0f;
        float xx = (float)(kx - 3) / 3.0f;
        float r0 = ct * yy - st * xx;
        float r1 = st * yy + ct * xx;
        if (q == 0)   // radius-1 points INCLUDED (fp32 ref); next r^2 = 10/9
            masks[p] = (r0 * r0 + r1 * r1 <= 1.00001f) ? 1.0f : 0.0f;
        #pragma unroll
        for (int jo = 0; jo < 8; ++jo) {
            int j = q * 8 + jo;
            float a = r0 * W1[j] + r1 * W1[32 + j] + ag * W1[64 + j] + b1[j];
            h1s[p][j] = __sinf(10.0f * a);
        }
    }
    __syncthreads();
    if (tid < 196) {
        int p = tid >> 2, q = tid & 3;
        #pragma unroll
        for (int jo = 0; jo < 8; ++jo) {
            int j = q * 8 + jo;
            float a = b2[j];
            #pragma unroll
            for (int i = 0; i < HID_; ++i) a += h1s[p][i] * W2[i * HID_ + j];
            h2s[p][j] = __sinf(10.0f * a);
        }
    }
    __syncthreads();
    for (int rep = 0; rep < 4; ++rep) {
        int o = rep * 256 + tid;             // cout*32 + cin
        float w3c[HID_];
        #pragma unroll
        for (int i = 0; i < HID_; ++i) w3c[i] = W3[i * 1024 + o];
        float bb = b3[o];
        int cout = o >> 5, cin = o & 31;
        int k = cin * G_ + gin;
        int n = gout * COUT_ + cout;
        int kc = k >> 5, hi = (k >> 3) & 3, jj = k & 7;
        bf16_t* dst = w2out + (((size_t)kc * 4 + hi) * 256 + n) * 8 + jj;
        for (int p = 0; p < 49; ++p) {
            float a = bb;
            #pragma unroll
            for (int i = 0; i < HID_; ++i) a += h2s[p][i] * w3c[i];
            a *= masks[p];
            dst[(size_t)p * (8 * 4 * 256 * 8)] = (bf16_t)a;
        }
    }
}

// ---------------------------------------------------------------------------
// Conv: implicit GEMM, block = (b, h-pair), wave = 64-wide N-strip covering
// full M=128 (2 image rows x 64 w), now on v_mfma_f32_32x32x16_bf16.
//
// R6 change: 16x16x32 -> 32x32x16 MFMA.  Identical FLOPs, 17% fewer matrix-
// pipe cycles (8.07 cyc/32K FLOP vs 4.85/16K; 2382 vs 2075 TF ubench) —
// R5 showed conv at 77% of the 16x16 pipe ceiling, so the shape IS the
// ceiling.  Operand layouts by symmetry with the verified 16x16x32 mapping:
//   A: row = lane&31 (w), k-octet = lane>>5  (xp chunk layout unchanged)
//   B: col = lane&31 (n), k-octet = lane>>5  (w2 layout unchanged; ko=ks*2+hl)
//   C/D (m74/m101-verified): col = lane&31, row = (reg&3)+8*(reg>>2)+4*(lane>>5)
// Per tap: 16 k-steps of {2 B-loads, 4 ds_read_b128, 8 MFMA}; same
// bytes/FLOP as R5; same cur/nxt 1-step-ahead rotation, uniform B base +
// compile-time immediates, s_setprio around each MFMA cluster.
#define CONV_STEP(AC, AN, BC, BN, PC, PB, AOF)                                \
  do {                                                                        \
    BN[0] = *reinterpret_cast<const bf16x8*>(                                 \
        (PB) + wlane_off + (PC) * 4096);                                      \
    BN[1] = *reinterpret_cast<const bf16x8*>(                                 \
        (PB) + wlane_off + (PC) * 4096 + 256);                                \
    _Pragma("unroll")                                                         \
    for (int mt = 0; mt < 2; ++mt) {                                          \
      AN[mt]     = *reinterpret_cast<const bf16x8*>(                          \
          aA + ((PC) * 2 * WP_ + mt * 32) * 8 + (AOF));                       \
      AN[mt + 2] = *reinterpret_cast<const bf16x8*>(                          \
          aB + ((PC) * 2 * WP_ + mt * 32) * 8 + (AOF));                       \
    }                                                                         \
    __builtin_amdgcn_s_setprio(1);                                            \
    _Pragma("unroll")                                                         \
    for (int mt = 0; mt < 4; ++mt)                                            \
      _Pragma("unroll")                                                       \
      for (int nt = 0; nt < 2; ++nt)                                          \
        acc[mt][nt] = __builtin_amdgcn_mfma_f32_32x32x16_bf16(                \
            AC[mt], BC[nt], acc[mt][nt], 0, 0, 0);                            \
    __builtin_amdgcn_s_setprio(0);                                            \
  } while (0)

__launch_bounds__(256, 2)
__global__ void conv_mfma(const bf16_t* __restrict__ xp,
                          const bf16_t* __restrict__ w2,
                          const float* __restrict__ bias,
                          float* __restrict__ out) {
    __shared__ __align__(16) bf16_t lds[2][ROW_ELEMS];   // 71,680 B
    int blk = blockIdx.x;             // b*32 + hpair
    int b = blk >> 5, h0 = (blk & 31) << 1;
    int tid = threadIdx.x;
    int ns = tid >> 6, lane = tid & 63;
    int c31 = lane & 31, hl = lane >> 5;
    // B lane offset: ko-part (hl) + n-part (ns*64 + c31); divergent, invariant
    int wlane_off = hl * 2048 + (ns * 64 + c31) * 8;

    f32x16 acc[4][2];
    #pragma unroll
    for (int i = 0; i < 4; ++i)
        #pragma unroll
        for (int j = 0; j < 2; ++j)
            #pragma unroll
            for (int e = 0; e < 16; ++e)
                acc[i][j][e] = 0.0f;

    const bf16_t* rows = xp + (((size_t)(b * WP_) + h0)) * ROW_ELEMS;
    // init: stage rows h0 (slot0) and h0+1 (slot1): 70 chunks of 1KB, linear
    for (int c = ns; c < 70; c += 4)
        dma16(rows + (size_t)c * 512 + lane * 8, &lds[0][0] + c * 512);

    // B prologue: prefetch (tap 0, ks 0)
    bf16x8 bcur[2], bnxt[2];
    bcur[0] = *reinterpret_cast<const bf16x8*>(w2 + wlane_off);
    bcur[1] = *reinterpret_cast<const bf16x8*>(w2 + wlane_off + 256);
    __syncthreads();   // drains init DMA (vmcnt 0) before LDS reads

    for (int ky = 0; ky < KS_; ++ky) {
        const bf16_t* slotA = &lds[ky & 1][0];        // image row h0+ky   (mt 0-1)
        const bf16_t* slotB = &lds[(ky + 1) & 1][0];  // image row h0+ky+1 (mt 2-3)
        // A(ks=0) prologue for this ky at kx=0
        bf16x8 acur[4], anxt[4];
        #pragma unroll
        for (int mt = 0; mt < 2; ++mt) {
            int xr = (hl * WP_ + c31 + mt * 32) * 8;
            acur[mt]     = *reinterpret_cast<const bf16x8*>(&slotA[xr]);
            acur[mt + 2] = *reinterpret_cast<const bf16x8*>(&slotB[xr]);
        }
        #pragma unroll 1
        for (int kx = 0; kx < 7; ++kx) {
            const bf16_t* wkx = w2 + (size_t)(ky * 7 + kx) * 65536;  // uniform
            const bf16_t* wnx = (ky == 6 && kx == 6) ? wkx : wkx + 65536;
            const bf16_t* aA = slotA + (hl * WP_ + c31 + kx) * 8;
            const bf16_t* aB = slotB + (hl * WP_ + c31 + kx) * 8;
            CONV_STEP(acur, anxt, bcur, bnxt,  1, wkx, 0);
            CONV_STEP(anxt, acur, bnxt, bcur,  2, wkx, 0);
            CONV_STEP(acur, anxt, bcur, bnxt,  3, wkx, 0);
            CONV_STEP(anxt, acur, bnxt, bcur,  4, wkx, 0);
            CONV_STEP(acur, anxt, bcur, bnxt,  5, wkx, 0);
            CONV_STEP(anxt, acur, bnxt, bcur,  6, wkx, 0);
            CONV_STEP(acur, anxt, bcur, bnxt,  7, wkx, 0);
            CONV_STEP(anxt, acur, bnxt, bcur,  8, wkx, 0);
            CONV_STEP(acur, anxt, bcur, bnxt,  9, wkx, 0);
            CONV_STEP(anxt, acur, bnxt, bcur, 10, wkx, 0);
            CONV_STEP(acur, anxt, bcur, bnxt, 11, wkx, 0);
            CONV_STEP(anxt, acur, bnxt, bcur, 12, wkx, 0);
            CONV_STEP(acur, anxt, bcur, bnxt, 13, wkx, 0);
            CONV_STEP(anxt, acur, bnxt, bcur, 14, wkx, 0);
            CONV_STEP(acur, anxt, bcur, bnxt, 15, wkx, 0);
            CONV_STEP(anxt, acur, bnxt, bcur,  0, wnx, 8);  // next kx/ky (ks=0); A dead at kx=6
        }
        if (ky < KS_ - 1) {
            __syncthreads();   // all waves done with row h0+ky (slot ky&1)
            bf16_t* dstslot = &lds[ky & 1][0];
            const bf16_t* src = rows + (size_t)(ky + 2) * ROW_ELEMS;
            for (int c = ns; c < 35; c += 4)
                dma16(src + (size_t)c * 512 + lane * 8, dstslot + c * 512);
            __syncthreads();   // drain DMA
        }
    }

    // epilogue: tile (mt,nt): col n = ns*64 + nt*32 + c31 (gout = ns*2+nt,
    // cout = c31, lane-uniform bias); row M = mt*32 + (reg&3)+8*(reg>>2)+4*hl
    // -> h = h0 + (mt>>1), w = 32*(mt&1) + 4*hl + 8*rq + {0..3}: f32x4 stores.
    float bv = bias[c31];
    #pragma unroll
    for (int mt = 0; mt < 4; ++mt) {
        int h = h0 + (mt >> 1);
        int wb0 = (mt & 1) * 32 + hl * 4;
        #pragma unroll
        for (int nt = 0; nt < 2; ++nt) {
            int gout = ns * 2 + nt;
            float* plane = out + (((size_t)(b * COUT_ + c31) * G_ + gout) * (H_ * W_))
                         + h * W_;
            #pragma unroll
            for (int rq = 0; rq < 4; ++rq) {
                f32x4 v;
                v[0] = acc[mt][nt][rq * 4 + 0] + bv;
                v[1] = acc[mt][nt][rq * 4 + 1] + bv;
                v[2] = acc[mt][nt][rq * 4 + 2] + bv;
                v[3] = acc[mt][nt][rq * 4 + 3] + bv;
                *reinterpret_cast<f32x4*>(plane + wb0 + rq * 8) = v;
            }
        }
    }
}

// ---------------------------------------------------------------------------
extern "C" void kernel_launch(void* const* d_in, const int* in_sizes, int n_in,
                              void* d_out, int out_size, void* d_ws, size_t ws_size,
                              hipStream_t stream) {
    const float* x      = (const float*)d_in[0];
    const float* thetas = (const float*)d_in[1];
    const float* W1     = (const float*)d_in[2];
    const float* b1     = (const float*)d_in[3];
    const float* W2     = (const float*)d_in[4];
    const float* b2     = (const float*)d_in[5];
    const float* W3     = (const float*)d_in[6];
    const float* b3     = (const float*)d_in[7];
    const float* bias   = (const float*)d_in[8];
    float* out = (float*)d_out;

    bf16_t* xp = (bf16_t*)d_ws;
    bf16_t* w2 = (bf16_t*)((char*)d_ws + XP_BYTES);

    hipLaunchKernelGGL(prep, dim3(REPACK_BLOCKS + GENW_BLOCKS), dim3(256), 0, stream,
                       x, xp, thetas, W1, b1, W2, b2, W3, b3, w2);
    hipLaunchKernelGGL(conv_mfma, dim3(CONV_BLOCKS), dim3(256), 0, stream,
                       xp, w2, bias, out);
}

// Round 8
// 485.533 us; speedup vs baseline: 1.0416x; 1.0416x over previous
//
#include <hip/hip_runtime.h>
#include <math.h>

typedef __bf16 bf16_t;
typedef __bf16 bf16x8 __attribute__((ext_vector_type(8)));
typedef float  f32x4  __attribute__((ext_vector_type(4)));
typedef float  f32x16 __attribute__((ext_vector_type(16)));

#define B_    16
#define CIN_  32
#define COUT_ 32
#define G_    8
#define CH_   256      // Cin*Gin = K channels per tap
#define H_    64
#define W_    64
#define HID_  32
#define KS_   7
#define PAD_  3
#define WP_   70       // W + 2*PAD

// xp layout: [B][y(70)][c16(32)][x(70)][8ch]  (chunk-major rows).
#define ROW_ELEMS  (WP_ * CH_)                                // 17,920 per row
#define XP_ELEMS   ((size_t)B_ * WP_ * ROW_ELEMS)             // 20,070,400
#define XP_BYTES   (XP_ELEMS * 2)                             // 40,140,800

#define REPACK_BLOCKS (B_ * (H_ + 6))                         // 1120
#define GENW_BLOCKS   (G_ * G_)                               // 64
#define CONV_BLOCKS   (B_ * (H_ / 2))                         // 512 = 2/CU exactly

static __device__ __forceinline__ unsigned pack_bf16(float a, float b) {
    union { __bf16 h; unsigned short u; } ua, ub;
    ua.h = (__bf16)a; ub.h = (__bf16)b;
    return (unsigned)ua.u | ((unsigned)ub.u << 16);
}

static __device__ __forceinline__ void dma16(const bf16_t* g, bf16_t* l) {
    __builtin_amdgcn_global_load_lds(
        (const __attribute__((address_space(1))) void*)g,
        (__attribute__((address_space(3))) void*)l, 16, 0, 0);
}

// ---------------------------------------------------------------------------
// Fused prep — EXACT R0 version (empirically fastest; R1/R4 gen_w re-blocks
// both regressed ~70-100us).  repack blocks FIRST, gen_w LAST; gen_w block =
// (gout,gin) with W3 register reuse across all 49 taps.  FROZEN.
__global__ void prep(const float* __restrict__ x, bf16_t* __restrict__ xp,
                     const float* __restrict__ thetas,
                     const float* __restrict__ W1, const float* __restrict__ b1,
                     const float* __restrict__ W2, const float* __restrict__ b2,
                     const float* __restrict__ W3, const float* __restrict__ b3,
                     bf16_t* __restrict__ w2out) {
    __shared__ float h1s[49][33];
    __shared__ float h2s[49][33];
    __shared__ float masks[49];
    int tid = threadIdx.x;
    if (blockIdx.x < REPACK_BLOCKS) {
        // ---------------- repack path ----------------
        int blk = blockIdx.x;
        int b = blk / (H_ + 6), hy = blk % (H_ + 6);
        const int4 z4 = make_int4(0, 0, 0, 0);
        if (hy >= H_) {
            int idx = hy - H_;
            int y = (idx < 3) ? idx : idx + 64;   // 0,1,2,67,68,69
            bf16_t* dst = xp + ((size_t)(b * WP_) + y) * ROW_ELEMS;
            for (int i = tid; i < ROW_ELEMS / 8; i += 256)
                *reinterpret_cast<int4*>(dst + (size_t)i * 8) = z4;
            return;
        }
        int lane = tid & 63, wv = tid >> 6;
        int r = lane >> 3;          // channel offset in tile -> w offset after T
        int t = lane & 7;           // w-chunk
        size_t orow = ((size_t)(b * WP_) + (hy + 3)) * ROW_ELEMS;
        for (int it = 0; it < 8; ++it) {
            int c0 = wv * 8 + it * 32;
            const float* src = x + ((size_t)(b * CH_ + c0 + r)) * (H_ * W_)
                                 + (size_t)hy * W_ + t * 8;
            float4 f0 = *reinterpret_cast<const float4*>(src);
            float4 f1 = *reinterpret_cast<const float4*>(src + 4);
            int d0 = (int)pack_bf16(f0.x, f0.y);
            int d1 = (int)pack_bf16(f0.z, f0.w);
            int d2 = (int)pack_bf16(f1.x, f1.y);
            int d3 = (int)pack_bf16(f1.z, f1.w);
            int p0, p1, p2, p3;
            p0 = __shfl_xor(d0, 32); p1 = __shfl_xor(d1, 32);
            p2 = __shfl_xor(d2, 32); p3 = __shfl_xor(d3, 32);
            if ((r & 4) == 0) { d2 = p0; d3 = p1; } else { d0 = p2; d1 = p3; }
            p0 = __shfl_xor(d0, 16); p1 = __shfl_xor(d1, 16);
            p2 = __shfl_xor(d2, 16); p3 = __shfl_xor(d3, 16);
            if ((r & 2) == 0) { d1 = p0; d3 = p2; } else { d0 = p1; d2 = p3; }
            p0 = __shfl_xor(d0, 8); p1 = __shfl_xor(d1, 8);
            p2 = __shfl_xor(d2, 8); p3 = __shfl_xor(d3, 8);
            if ((r & 1) == 0) {
                d0 = (d0 & 0xFFFF) | (p0 << 16);
                d1 = (d1 & 0xFFFF) | (p1 << 16);
                d2 = (d2 & 0xFFFF) | (p2 << 16);
                d3 = (d3 & 0xFFFF) | (p3 << 16);
            } else {
                d0 = (d0 & 0xFFFF0000) | ((unsigned)p0 >> 16);
                d1 = (d1 & 0xFFFF0000) | ((unsigned)p1 >> 16);
                d2 = (d2 & 0xFFFF0000) | ((unsigned)p2 >> 16);
                d3 = (d3 & 0xFFFF0000) | ((unsigned)p3 >> 16);
            }
            int xpos = t * 8 + r + 3;
            int c16 = c0 >> 3;
            int4 v = make_int4(d0, d1, d2, d3);
            // chunk-major: wave's 64 stores cover one contiguous 1024B run
            *reinterpret_cast<int4*>(xp + orow + ((size_t)c16 * WP_ + xpos) * 8) = v;
        }
        if (tid < 192) {   // zero w-border cols {0,1,2,67,68,69} in every chunk
            int col = tid >> 5, cg = tid & 31;
            int xx = (col < 3) ? col : col + 64;
            *reinterpret_cast<int4*>(xp + orow + ((size_t)cg * WP_ + xx) * 8) = z4;
        }
        return;
    }
    // ---------------- gen_w path: block = (gout, gin) ----------------
    int blk = blockIdx.x - REPACK_BLOCKS;
    int gin = blk & 7, gout = blk >> 3;
    const float TWO_PI = 6.283185307179586f;
    const float PI_F   = 3.14159265358979323846f;
    float th_o = thetas[gout], th_i = thetas[gin];
    float d = fmodf(th_i - th_o, TWO_PI);
    if (d < 0.0f) d += TWO_PI;
    float ag = d / PI_F - 1.0f;
    float ct = cosf(-th_o), st = sinf(-th_o);

    if (tid < 196) {
        int p = tid >> 2, q = tid & 3;       // tap, j-octet
        int ky = p / 7, kx = p % 7;
        float yy = (float)(ky - 3) / 3.0f;
        float xx = (float)(kx - 3) / 3.0f;
        float r0 = ct * yy - st * xx;
        float r1 = st * yy + ct * xx;
        if (q == 0)   // radius-1 points INCLUDED (fp32 ref); next r^2 = 10/9
            masks[p] = (r0 * r0 + r1 * r1 <= 1.00001f) ? 1.0f : 0.0f;
        #pragma unroll
        for (int jo = 0; jo < 8; ++jo) {
            int j = q * 8 + jo;
            float a = r0 * W1[j] + r1 * W1[32 + j] + ag * W1[64 + j] + b1[j];
            h1s[p][j] = __sinf(10.0f * a);
        }
    }
    __syncthreads();
    if (tid < 196) {
        int p = tid >> 2, q = tid & 3;
        #pragma unroll
        for (int jo = 0; jo < 8; ++jo) {
            int j = q * 8 + jo;
            float a = b2[j];
            #pragma unroll
            for (int i = 0; i < HID_; ++i) a += h1s[p][i] * W2[i * HID_ + j];
            h2s[p][j] = __sinf(10.0f * a);
        }
    }
    __syncthreads();
    for (int rep = 0; rep < 4; ++rep) {
        int o = rep * 256 + tid;             // cout*32 + cin
        float w3c[HID_];
        #pragma unroll
        for (int i = 0; i < HID_; ++i) w3c[i] = W3[i * 1024 + o];
        float bb = b3[o];
        int cout = o >> 5, cin = o & 31;
        int k = cin * G_ + gin;
        int n = gout * COUT_ + cout;
        int kc = k >> 5, hi = (k >> 3) & 3, jj = k & 7;
        bf16_t* dst = w2out + (((size_t)kc * 4 + hi) * 256 + n) * 8 + jj;
        for (int p = 0; p < 49; ++p) {
            float a = bb;
            #pragma unroll
            for (int i = 0; i < HID_; ++i) a += h2s[p][i] * w3c[i];
            a *= masks[p];
            dst[(size_t)p * (8 * 4 * 256 * 8)] = (bf16_t)a;
        }
    }
}

// ---------------------------------------------------------------------------
// Conv: implicit GEMM on v_mfma_f32_32x32x16_bf16 (R6 layouts, HW-verified).
//
// R8 = R7 with the A-prefetch bug fixed: the final step of each tap must
// prefetch A(kx+1, ks=0) -> PCA=0 (R7 passed PCA=15, feeding the next tap's
// first step a stale ks=15 fragment; absmax 19.75).  B pipeline unchanged:
// 2-step-ahead, 4 named buffers b0..b3 (period 4 | 16 steps/tap), all
// compile-time indices.  Rationale (R6 counters: conflicts 0, VALU 9.8%,
// MfmaUtil 58%): the exposed stall is B-load latency — the 8-MFMA burst
// (~270 cyc) is shorter than L2/HBM B-latency (w2 6.4MB > 4MB/XCD L2);
// 2-deep gives ~540 cyc of cover.  A stays 1-step (LDS ~120 cyc).
//   A: row = lane&31 (w), k-octet = lane>>5   (xp chunk layout)
//   B: col = lane&31 (n), k-octet ko = ks*2 + (lane>>5)  (w2 layout)
//   C/D: col = lane&31, row = (reg&3)+8*(reg>>2)+4*(lane>>5)
#define CONV_STEP(AC, AN, BC, BN, PCA, PBB, PCB, AOF)                         \
  do {                                                                        \
    BN[0] = *reinterpret_cast<const bf16x8*>(                                 \
        (PBB) + wlane_off + (PCB) * 4096);                                    \
    BN[1] = *reinterpret_cast<const bf16x8*>(                                 \
        (PBB) + wlane_off + (PCB) * 4096 + 256);                              \
    _Pragma("unroll")                                                         \
    for (int mt = 0; mt < 2; ++mt) {                                          \
      AN[mt]     = *reinterpret_cast<const bf16x8*>(                          \
          aA + ((PCA) * 2 * WP_ + mt * 32) * 8 + (AOF));                      \
      AN[mt + 2] = *reinterpret_cast<const bf16x8*>(                          \
          aB + ((PCA) * 2 * WP_ + mt * 32) * 8 + (AOF));                      \
    }                                                                         \
    __builtin_amdgcn_s_setprio(1);                                            \
    _Pragma("unroll")                                                         \
    for (int mt = 0; mt < 4; ++mt)                                            \
      _Pragma("unroll")                                                       \
      for (int nt = 0; nt < 2; ++nt)                                          \
        acc[mt][nt] = __builtin_amdgcn_mfma_f32_32x32x16_bf16(                \
            AC[mt], BC[nt], acc[mt][nt], 0, 0, 0);                            \
    __builtin_amdgcn_s_setprio(0);                                            \
  } while (0)

__launch_bounds__(256, 2)
__global__ void conv_mfma(const bf16_t* __restrict__ xp,
                          const bf16_t* __restrict__ w2,
                          const float* __restrict__ bias,
                          float* __restrict__ out) {
    __shared__ __align__(16) bf16_t lds[2][ROW_ELEMS];   // 71,680 B
    int blk = blockIdx.x;             // b*32 + hpair
    int b = blk >> 5, h0 = (blk & 31) << 1;
    int tid = threadIdx.x;
    int ns = tid >> 6, lane = tid & 63;
    int c31 = lane & 31, hl = lane >> 5;
    // B lane offset: ko-part (hl) + n-part (ns*64 + c31); divergent, invariant
    int wlane_off = hl * 2048 + (ns * 64 + c31) * 8;

    f32x16 acc[4][2];
    #pragma unroll
    for (int i = 0; i < 4; ++i)
        #pragma unroll
        for (int j = 0; j < 2; ++j)
            #pragma unroll
            for (int e = 0; e < 16; ++e)
                acc[i][j][e] = 0.0f;

    const bf16_t* rows = xp + (((size_t)(b * WP_) + h0)) * ROW_ELEMS;
    // init: stage rows h0 (slot0) and h0+1 (slot1): 70 chunks of 1KB, linear
    for (int c = ns; c < 70; c += 4)
        dma16(rows + (size_t)c * 512 + lane * 8, &lds[0][0] + c * 512);

    // B prologue: prefetch (tap 0, ks 0) and (tap 0, ks 1)
    bf16x8 b0[2], b1[2], b2[2], b3[2];
    b0[0] = *reinterpret_cast<const bf16x8*>(w2 + wlane_off);
    b0[1] = *reinterpret_cast<const bf16x8*>(w2 + wlane_off + 256);
    b1[0] = *reinterpret_cast<const bf16x8*>(w2 + wlane_off + 4096);
    b1[1] = *reinterpret_cast<const bf16x8*>(w2 + wlane_off + 4096 + 256);
    __syncthreads();   // drains init DMA (vmcnt 0) before LDS reads

    for (int ky = 0; ky < KS_; ++ky) {
        const bf16_t* slotA = &lds[ky & 1][0];        // image row h0+ky   (mt 0-1)
        const bf16_t* slotB = &lds[(ky + 1) & 1][0];  // image row h0+ky+1 (mt 2-3)
        // A(ks=0) prologue for this ky at kx=0
        bf16x8 acur[4], anxt[4];
        #pragma unroll
        for (int mt = 0; mt < 2; ++mt) {
            int xr = (hl * WP_ + c31 + mt * 32) * 8;
            acur[mt]     = *reinterpret_cast<const bf16x8*>(&slotA[xr]);
            acur[mt + 2] = *reinterpret_cast<const bf16x8*>(&slotB[xr]);
        }
        #pragma unroll 1
        for (int kx = 0; kx < 7; ++kx) {
            const bf16_t* wkx = w2 + (size_t)(ky * 7 + kx) * 65536;  // uniform
            const bf16_t* wnx = (ky == 6 && kx == 6) ? wkx : wkx + 65536;
            const bf16_t* aA = slotA + (hl * WP_ + c31 + kx) * 8;
            const bf16_t* aB = slotB + (hl * WP_ + c31 + kx) * 8;
            // step j: uses A(j), B(ks j); prefetches A(j+1), B(ks j+2)
            CONV_STEP(acur, anxt, b0, b2,  1, wkx,  2, 0);
            CONV_STEP(anxt, acur, b1, b3,  2, wkx,  3, 0);
            CONV_STEP(acur, anxt, b2, b0,  3, wkx,  4, 0);
            CONV_STEP(anxt, acur, b3, b1,  4, wkx,  5, 0);
            CONV_STEP(acur, anxt, b0, b2,  5, wkx,  6, 0);
            CONV_STEP(anxt, acur, b1, b3,  6, wkx,  7, 0);
            CONV_STEP(acur, anxt, b2, b0,  7, wkx,  8, 0);
            CONV_STEP(anxt, acur, b3, b1,  8, wkx,  9, 0);
            CONV_STEP(acur, anxt, b0, b2,  9, wkx, 10, 0);
            CONV_STEP(anxt, acur, b1, b3, 10, wkx, 11, 0);
            CONV_STEP(acur, anxt, b2, b0, 11, wkx, 12, 0);
            CONV_STEP(anxt, acur, b3, b1, 12, wkx, 13, 0);
            CONV_STEP(acur, anxt, b0, b2, 13, wkx, 14, 0);
            CONV_STEP(anxt, acur, b1, b3, 14, wkx, 15, 0);
            CONV_STEP(acur, anxt, b2, b0, 15, wnx,  0, 0);  // step14: pre anxt=A(15), b0<-B(tap+1,ks0)
            CONV_STEP(anxt, acur, b3, b1,  0, wnx,  1, 8);  // step15: pre acur=A(kx+1,ks0), b1<-B(tap+1,ks1)
        }
        if (ky < KS_ - 1) {
            __syncthreads();   // all waves done with row h0+ky (slot ky&1)
            bf16_t* dstslot = &lds[ky & 1][0];
            const bf16_t* src = rows + (size_t)(ky + 2) * ROW_ELEMS;
            for (int c = ns; c < 35; c += 4)
                dma16(src + (size_t)c * 512 + lane * 8, dstslot + c * 512);
            __syncthreads();   // drain DMA
        }
    }

    // epilogue: tile (mt,nt): col n = ns*64 + nt*32 + c31 (gout = ns*2+nt,
    // cout = c31, lane-uniform bias); row M = mt*32 + (reg&3)+8*(reg>>2)+4*hl
    // -> h = h0 + (mt>>1), w = 32*(mt&1) + 4*hl + 8*rq + {0..3}: f32x4 stores.
    float bv = bias[c31];
    #pragma unroll
    for (int mt = 0; mt < 4; ++mt) {
        int h = h0 + (mt >> 1);
        int wb0 = (mt & 1) * 32 + hl * 4;
        #pragma unroll
        for (int nt = 0; nt < 2; ++nt) {
            int gout = ns * 2 + nt;
            float* plane = out + (((size_t)(b * COUT_ + c31) * G_ + gout) * (H_ * W_))
                         + h * W_;
            #pragma unroll
            for (int rq = 0; rq < 4; ++rq) {
                f32x4 v;
                v[0] = acc[mt][nt][rq * 4 + 0] + bv;
                v[1] = acc[mt][nt][rq * 4 + 1] + bv;
                v[2] = acc[mt][nt][rq * 4 + 2] + bv;
                v[3] = acc[mt][nt][rq * 4 + 3] + bv;
                *reinterpret_cast<f32x4*>(plane + wb0 + rq * 8) = v;
            }
        }
    }
}

// ---------------------------------------------------------------------------
extern "C" void kernel_launch(void* const* d_in, const int* in_sizes, int n_in,
                              void* d_out, int out_size, void* d_ws, size_t ws_size,
                              hipStream_t stream) {
    const float* x      = (const float*)d_in[0];
    const float* thetas = (const float*)d_in[1];
    const float* W1     = (const float*)d_in[2];
    const float* b1     = (const float*)d_in[3];
    const float* W2     = (const float*)d_in[4];
    const float* b2     = (const float*)d_in[5];
    const float* W3     = (const float*)d_in[6];
    const float* b3     = (const float*)d_in[7];
    const float* bias   = (const float*)d_in[8];
    float* out = (float*)d_out;

    bf16_t* xp = (bf16_t*)d_ws;
    bf16_t* w2 = (bf16_t*)((char*)d_ws + XP_BYTES);

    hipLaunchKernelGGL(prep, dim3(REPACK_BLOCKS + GENW_BLOCKS), dim3(256), 0, stream,
                       x, xp, thetas, W1, b1, W2, b2, W3, b3, w2);
    hipLaunchKernelGGL(conv_mfma, dim3(CONV_BLOCKS), dim3(256), 0, stream,
                       xp, w2, bias, out);
}

// Round 9
// 483.867 us; speedup vs baseline: 1.0452x; 1.0034x over previous
//
#include <hip/hip_runtime.h>
#include <math.h>

typedef __bf16 bf16_t;
typedef __bf16 bf16x8 __attribute__((ext_vector_type(8)));
typedef float  f32x4  __attribute__((ext_vector_type(4)));
typedef float  f32x16 __attribute__((ext_vector_type(16)));

#define B_    16
#define CIN_  32
#define COUT_ 32
#define G_    8
#define CH_   256      // Cin*Gin = K channels per tap
#define H_    64
#define W_    64
#define HID_  32
#define KS_   7
#define PAD_  3
#define WP_   70       // W + 2*PAD

// xp layout: [B][y(70)][c16(32)][x(70)][8ch]  (chunk-major rows).
#define ROW_ELEMS  (WP_ * CH_)                                // 17,920 per row
#define XP_ELEMS   ((size_t)B_ * WP_ * ROW_ELEMS)             // 20,070,400
#define XP_BYTES   (XP_ELEMS * 2)                             // 40,140,800

#define REPACK_BLOCKS (B_ * (H_ + 6))                         // 1120
#define GENW_BLOCKS   (G_ * G_)                               // 64
#define CONV_BLOCKS   (B_ * (H_ / 2))                         // 512 = 2/CU exactly

static __device__ __forceinline__ unsigned pack_bf16(float a, float b) {
    union { __bf16 h; unsigned short u; } ua, ub;
    ua.h = (__bf16)a; ub.h = (__bf16)b;
    return (unsigned)ua.u | ((unsigned)ub.u << 16);
}

static __device__ __forceinline__ void dma16(const bf16_t* g, bf16_t* l) {
    __builtin_amdgcn_global_load_lds(
        (const __attribute__((address_space(1))) void*)g,
        (__attribute__((address_space(3))) void*)l, 16, 0, 0);
}

// ---------------------------------------------------------------------------
// Fused prep — EXACT R0 version (empirically fastest; R1/R4 gen_w re-blocks
// both regressed ~70-100us).  repack blocks FIRST, gen_w LAST; gen_w block =
// (gout,gin) with W3 register reuse across all 49 taps.  FROZEN.
__global__ void prep(const float* __restrict__ x, bf16_t* __restrict__ xp,
                     const float* __restrict__ thetas,
                     const float* __restrict__ W1, const float* __restrict__ b1,
                     const float* __restrict__ W2, const float* __restrict__ b2,
                     const float* __restrict__ W3, const float* __restrict__ b3,
                     bf16_t* __restrict__ w2out) {
    __shared__ float h1s[49][33];
    __shared__ float h2s[49][33];
    __shared__ float masks[49];
    int tid = threadIdx.x;
    if (blockIdx.x < REPACK_BLOCKS) {
        // ---------------- repack path ----------------
        int blk = blockIdx.x;
        int b = blk / (H_ + 6), hy = blk % (H_ + 6);
        const int4 z4 = make_int4(0, 0, 0, 0);
        if (hy >= H_) {
            int idx = hy - H_;
            int y = (idx < 3) ? idx : idx + 64;   // 0,1,2,67,68,69
            bf16_t* dst = xp + ((size_t)(b * WP_) + y) * ROW_ELEMS;
            for (int i = tid; i < ROW_ELEMS / 8; i += 256)
                *reinterpret_cast<int4*>(dst + (size_t)i * 8) = z4;
            return;
        }
        int lane = tid & 63, wv = tid >> 6;
        int r = lane >> 3;          // channel offset in tile -> w offset after T
        int t = lane & 7;           // w-chunk
        size_t orow = ((size_t)(b * WP_) + (hy + 3)) * ROW_ELEMS;
        for (int it = 0; it < 8; ++it) {
            int c0 = wv * 8 + it * 32;
            const float* src = x + ((size_t)(b * CH_ + c0 + r)) * (H_ * W_)
                                 + (size_t)hy * W_ + t * 8;
            float4 f0 = *reinterpret_cast<const float4*>(src);
            float4 f1 = *reinterpret_cast<const float4*>(src + 4);
            int d0 = (int)pack_bf16(f0.x, f0.y);
            int d1 = (int)pack_bf16(f0.z, f0.w);
            int d2 = (int)pack_bf16(f1.x, f1.y);
            int d3 = (int)pack_bf16(f1.z, f1.w);
            int p0, p1, p2, p3;
            p0 = __shfl_xor(d0, 32); p1 = __shfl_xor(d1, 32);
            p2 = __shfl_xor(d2, 32); p3 = __shfl_xor(d3, 32);
            if ((r & 4) == 0) { d2 = p0; d3 = p1; } else { d0 = p2; d1 = p3; }
            p0 = __shfl_xor(d0, 16); p1 = __shfl_xor(d1, 16);
            p2 = __shfl_xor(d2, 16); p3 = __shfl_xor(d3, 16);
            if ((r & 2) == 0) { d1 = p0; d3 = p2; } else { d0 = p1; d2 = p3; }
            p0 = __shfl_xor(d0, 8); p1 = __shfl_xor(d1, 8);
            p2 = __shfl_xor(d2, 8); p3 = __shfl_xor(d3, 8);
            if ((r & 1) == 0) {
                d0 = (d0 & 0xFFFF) | (p0 << 16);
                d1 = (d1 & 0xFFFF) | (p1 << 16);
                d2 = (d2 & 0xFFFF) | (p2 << 16);
                d3 = (d3 & 0xFFFF) | (p3 << 16);
            } else {
                d0 = (d0 & 0xFFFF0000) | ((unsigned)p0 >> 16);
                d1 = (d1 & 0xFFFF0000) | ((unsigned)p1 >> 16);
                d2 = (d2 & 0xFFFF0000) | ((unsigned)p2 >> 16);
                d3 = (d3 & 0xFFFF0000) | ((unsigned)p3 >> 16);
            }
            int xpos = t * 8 + r + 3;
            int c16 = c0 >> 3;
            int4 v = make_int4(d0, d1, d2, d3);
            // chunk-major: wave's 64 stores cover one contiguous 1024B run
            *reinterpret_cast<int4*>(xp + orow + ((size_t)c16 * WP_ + xpos) * 8) = v;
        }
        if (tid < 192) {   // zero w-border cols {0,1,2,67,68,69} in every chunk
            int col = tid >> 5, cg = tid & 31;
            int xx = (col < 3) ? col : col + 64;
            *reinterpret_cast<int4*>(xp + orow + ((size_t)cg * WP_ + xx) * 8) = z4;
        }
        return;
    }
    // ---------------- gen_w path: block = (gout, gin) ----------------
    int blk = blockIdx.x - REPACK_BLOCKS;
    int gin = blk & 7, gout = blk >> 3;
    const float TWO_PI = 6.283185307179586f;
    const float PI_F   = 3.14159265358979323846f;
    float th_o = thetas[gout], th_i = thetas[gin];
    float d = fmodf(th_i - th_o, TWO_PI);
    if (d < 0.0f) d += TWO_PI;
    float ag = d / PI_F - 1.0f;
    float ct = cosf(-th_o), st = sinf(-th_o);

    if (tid < 196) {
        int p = tid >> 2, q = tid & 3;       // tap, j-octet
        int ky = p / 7, kx = p % 7;
        float yy = (float)(ky - 3) / 3.0f;
        float xx = (float)(kx - 3) / 3.0f;
        float r0 = ct * yy - st * xx;
        float r1 = st * yy + ct * xx;
        if (q == 0)   // radius-1 points INCLUDED (fp32 ref); next r^2 = 10/9
            masks[p] = (r0 * r0 + r1 * r1 <= 1.00001f) ? 1.0f : 0.0f;
        #pragma unroll
        for (int jo = 0; jo < 8; ++jo) {
            int j = q * 8 + jo;
            float a = r0 * W1[j] + r1 * W1[32 + j] + ag * W1[64 + j] + b1[j];
            h1s[p][j] = __sinf(10.0f * a);
        }
    }
    __syncthreads();
    if (tid < 196) {
        int p = tid >> 2, q = tid & 3;
        #pragma unroll
        for (int jo = 0; jo < 8; ++jo) {
            int j = q * 8 + jo;
            float a = b2[j];
            #pragma unroll
            for (int i = 0; i < HID_; ++i) a += h1s[p][i] * W2[i * HID_ + j];
            h2s[p][j] = __sinf(10.0f * a);
        }
    }
    __syncthreads();
    for (int rep = 0; rep < 4; ++rep) {
        int o = rep * 256 + tid;             // cout*32 + cin
        float w3c[HID_];
        #pragma unroll
        for (int i = 0; i < HID_; ++i) w3c[i] = W3[i * 1024 + o];
        float bb = b3[o];
        int cout = o >> 5, cin = o & 31;
        int k = cin * G_ + gin;
        int n = gout * COUT_ + cout;
        int kc = k >> 5, hi = (k >> 3) & 3, jj = k & 7;
        bf16_t* dst = w2out + (((size_t)kc * 4 + hi) * 256 + n) * 8 + jj;
        for (int p = 0; p < 49; ++p) {
            float a = bb;
            #pragma unroll
            for (int i = 0; i < HID_; ++i) a += h2s[p][i] * w3c[i];
            a *= masks[p];
            dst[(size_t)p * (8 * 4 * 256 * 8)] = (bf16_t)a;
        }
    }
}

// ---------------------------------------------------------------------------
// Conv: implicit GEMM on v_mfma_f32_32x32x16_bf16 (R6/R8 layouts, HW-verified).
//
// R9 change: fuse two K=16 slices per pipeline step -> per step {4 B-loads,
// 8 A ds_reads, 16 MFMA (~540 cyc burst)}, 8 steps/tap, 392 steps/wave.
// Rationale: R5 vs R8 decomposition showed a ~400 cyc FIXED bubble per
// step-pair (waitcnt seams + issue serialization), independent of shape and
// B-depth; R8 paid it 784x vs R5's 392x.  This restores R5's step count and
// per-step load pattern on the 32x32 shape (pipe floor 424K vs 486K cyc).
// 1-step-ahead cur/nxt rotation for BOTH streams (R5's proven formula;
// 540-cyc burst covers B L2 latency).  All offsets compile-time.
//   A: row = lane&31 (w), k-octet = lane>>5; chunk = ks*2 + hl
//   B: col = lane&31 (n), addr = wlane_off + ks*4096 + nt*256 elems
//   C/D: col = lane&31, row = (reg&3)+8*(reg>>2)+4*(lane>>5)
// Step j consumes ks-pair (2j,2j+1), prefetches pair (2j+2,2j+3) [or next
// tap's (0,1) at j=7, A from kx+1 via AOF=8 elems].
#define CONV_STEP2(AC, AN, BC, BN, PK, PBB, AOF)                              \
  do {                                                                        \
    BN[0] = *reinterpret_cast<const bf16x8*>(                                 \
        (PBB) + wlane_off + (PK) * 4096);                                     \
    BN[1] = *reinterpret_cast<const bf16x8*>(                                 \
        (PBB) + wlane_off + (PK) * 4096 + 256);                               \
    BN[2] = *reinterpret_cast<const bf16x8*>(                                 \
        (PBB) + wlane_off + ((PK) + 1) * 4096);                               \
    BN[3] = *reinterpret_cast<const bf16x8*>(                                 \
        (PBB) + wlane_off + ((PK) + 1) * 4096 + 256);                         \
    _Pragma("unroll")                                                         \
    for (int mt = 0; mt < 2; ++mt) {                                          \
      AN[mt]     = *reinterpret_cast<const bf16x8*>(                          \
          aA + ((PK) * 2 * WP_ + mt * 32) * 8 + (AOF));                       \
      AN[mt + 2] = *reinterpret_cast<const bf16x8*>(                          \
          aB + ((PK) * 2 * WP_ + mt * 32) * 8 + (AOF));                       \
      AN[mt + 4] = *reinterpret_cast<const bf16x8*>(                          \
          aA + (((PK) + 1) * 2 * WP_ + mt * 32) * 8 + (AOF));                 \
      AN[mt + 6] = *reinterpret_cast<const bf16x8*>(                          \
          aB + (((PK) + 1) * 2 * WP_ + mt * 32) * 8 + (AOF));                 \
    }                                                                         \
    __builtin_amdgcn_s_setprio(1);                                            \
    _Pragma("unroll")                                                         \
    for (int s = 0; s < 2; ++s)                                               \
      _Pragma("unroll")                                                       \
      for (int mt = 0; mt < 4; ++mt)                                          \
        _Pragma("unroll")                                                     \
        for (int nt = 0; nt < 2; ++nt)                                        \
          acc[mt][nt] = __builtin_amdgcn_mfma_f32_32x32x16_bf16(              \
              AC[s * 4 + mt], BC[s * 2 + nt], acc[mt][nt], 0, 0, 0);          \
    __builtin_amdgcn_s_setprio(0);                                            \
  } while (0)

__launch_bounds__(256, 2)
__global__ void conv_mfma(const bf16_t* __restrict__ xp,
                          const bf16_t* __restrict__ w2,
                          const float* __restrict__ bias,
                          float* __restrict__ out) {
    __shared__ __align__(16) bf16_t lds[2][ROW_ELEMS];   // 71,680 B
    int blk = blockIdx.x;             // b*32 + hpair
    int b = blk >> 5, h0 = (blk & 31) << 1;
    int tid = threadIdx.x;
    int ns = tid >> 6, lane = tid & 63;
    int c31 = lane & 31, hl = lane >> 5;
    // B lane offset: ko-part (hl) + n-part (ns*64 + c31); divergent, invariant
    int wlane_off = hl * 2048 + (ns * 64 + c31) * 8;

    f32x16 acc[4][2];
    #pragma unroll
    for (int i = 0; i < 4; ++i)
        #pragma unroll
        for (int j = 0; j < 2; ++j)
            #pragma unroll
            for (int e = 0; e < 16; ++e)
                acc[i][j][e] = 0.0f;

    const bf16_t* rows = xp + (((size_t)(b * WP_) + h0)) * ROW_ELEMS;
    // init: stage rows h0 (slot0) and h0+1 (slot1): 70 chunks of 1KB, linear
    for (int c = ns; c < 70; c += 4)
        dma16(rows + (size_t)c * 512 + lane * 8, &lds[0][0] + c * 512);

    // B prologue: prefetch (tap 0, ks 0 and 1)
    bf16x8 bcur[4], bnxt[4];
    bcur[0] = *reinterpret_cast<const bf16x8*>(w2 + wlane_off);
    bcur[1] = *reinterpret_cast<const bf16x8*>(w2 + wlane_off + 256);
    bcur[2] = *reinterpret_cast<const bf16x8*>(w2 + wlane_off + 4096);
    bcur[3] = *reinterpret_cast<const bf16x8*>(w2 + wlane_off + 4096 + 256);
    __syncthreads();   // drains init DMA (vmcnt 0) before LDS reads

    for (int ky = 0; ky < KS_; ++ky) {
        const bf16_t* slotA = &lds[ky & 1][0];        // image row h0+ky   (mt 0-1)
        const bf16_t* slotB = &lds[(ky + 1) & 1][0];  // image row h0+ky+1 (mt 2-3)
        // A(ks-pair 0,1) prologue for this ky at kx=0
        bf16x8 acur[8], anxt[8];
        {
            const bf16_t* pA = slotA + (hl * WP_ + c31) * 8;
            const bf16_t* pB = slotB + (hl * WP_ + c31) * 8;
            #pragma unroll
            for (int mt = 0; mt < 2; ++mt) {
                acur[mt]     = *reinterpret_cast<const bf16x8*>(pA + mt * 256);
                acur[mt + 2] = *reinterpret_cast<const bf16x8*>(pB + mt * 256);
                acur[mt + 4] = *reinterpret_cast<const bf16x8*>(pA + (2 * WP_ + mt * 32) * 8);
                acur[mt + 6] = *reinterpret_cast<const bf16x8*>(pB + (2 * WP_ + mt * 32) * 8);
            }
        }
        #pragma unroll 1
        for (int kx = 0; kx < 7; ++kx) {
            const bf16_t* wkx = w2 + (size_t)(ky * 7 + kx) * 65536;  // uniform
            const bf16_t* wnx = (ky == 6 && kx == 6) ? wkx : wkx + 65536;
            const bf16_t* aA = slotA + (hl * WP_ + c31 + kx) * 8;
            const bf16_t* aB = slotB + (hl * WP_ + c31 + kx) * 8;
            // step j: uses ks-pair (2j,2j+1); prefetches pair (2j+2,2j+3)
            CONV_STEP2(acur, anxt, bcur, bnxt,  2, wkx, 0);
            CONV_STEP2(anxt, acur, bnxt, bcur,  4, wkx, 0);
            CONV_STEP2(acur, anxt, bcur, bnxt,  6, wkx, 0);
            CONV_STEP2(anxt, acur, bnxt, bcur,  8, wkx, 0);
            CONV_STEP2(acur, anxt, bcur, bnxt, 10, wkx, 0);
            CONV_STEP2(anxt, acur, bnxt, bcur, 12, wkx, 0);
            CONV_STEP2(acur, anxt, bcur, bnxt, 14, wkx, 0);
            CONV_STEP2(anxt, acur, bnxt, bcur,  0, wnx, 8);  // next tap pair(0,1); A from kx+1 (dead at kx=6)
        }
        if (ky < KS_ - 1) {
            __syncthreads();   // all waves done with row h0+ky (slot ky&1)
            bf16_t* dstslot = &lds[ky & 1][0];
            const bf16_t* src = rows + (size_t)(ky + 2) * ROW_ELEMS;
            for (int c = ns; c < 35; c += 4)
                dma16(src + (size_t)c * 512 + lane * 8, dstslot + c * 512);
            __syncthreads();   // drain DMA
        }
    }

    // epilogue: tile (mt,nt): col n = ns*64 + nt*32 + c31 (gout = ns*2+nt,
    // cout = c31, lane-uniform bias); row M = mt*32 + (reg&3)+8*(reg>>2)+4*hl
    // -> h = h0 + (mt>>1), w = 32*(mt&1) + 4*hl + 8*rq + {0..3}: f32x4 stores.
    float bv = bias[c31];
    #pragma unroll
    for (int mt = 0; mt < 4; ++mt) {
        int h = h0 + (mt >> 1);
        int wb0 = (mt & 1) * 32 + hl * 4;
        #pragma unroll
        for (int nt = 0; nt < 2; ++nt) {
            int gout = ns * 2 + nt;
            float* plane = out + (((size_t)(b * COUT_ + c31) * G_ + gout) * (H_ * W_))
                         + h * W_;
            #pragma unroll
            for (int rq = 0; rq < 4; ++rq) {
                f32x4 v;
                v[0] = acc[mt][nt][rq * 4 + 0] + bv;
                v[1] = acc[mt][nt][rq * 4 + 1] + bv;
                v[2] = acc[mt][nt][rq * 4 + 2] + bv;
                v[3] = acc[mt][nt][rq * 4 + 3] + bv;
                *reinterpret_cast<f32x4*>(plane + wb0 + rq * 8) = v;
            }
        }
    }
}

// ---------------------------------------------------------------------------
extern "C" void kernel_launch(void* const* d_in, const int* in_sizes, int n_in,
                              void* d_out, int out_size, void* d_ws, size_t ws_size,
                              hipStream_t stream) {
    const float* x      = (const float*)d_in[0];
    const float* thetas = (const float*)d_in[1];
    const float* W1     = (const float*)d_in[2];
    const float* b1     = (const float*)d_in[3];
    const float* W2     = (const float*)d_in[4];
    const float* b2     = (const float*)d_in[5];
    const float* W3     = (const float*)d_in[6];
    const float* b3     = (const float*)d_in[7];
    const float* bias   = (const float*)d_in[8];
    float* out = (float*)d_out;

    bf16_t* xp = (bf16_t*)d_ws;
    bf16_t* w2 = (bf16_t*)((char*)d_ws + XP_BYTES);

    hipLaunchKernelGGL(prep, dim3(REPACK_BLOCKS + GENW_BLOCKS), dim3(256), 0, stream,
                       x, xp, thetas, W1, b1, W2, b2, W3, b3, w2);
    hipLaunchKernelGGL(conv_mfma, dim3(CONV_BLOCKS), dim3(256), 0, stream,
                       xp, w2, bias, out);
}

// Round 10
// 478.878 us; speedup vs baseline: 1.0561x; 1.0104x over previous
//
#include <hip/hip_runtime.h>
#include <math.h>

typedef __bf16 bf16_t;
typedef __bf16 bf16x8 __attribute__((ext_vector_type(8)));
typedef float  f32x4  __attribute__((ext_vector_type(4)));

#define B_    16
#define CIN_  32
#define COUT_ 32
#define G_    8
#define CH_   256      // Cin*Gin = K channels per tap
#define H_    64
#define W_    64
#define HID_  32
#define KS_   7
#define PAD_  3
#define WP_   70       // W + 2*PAD

// xp layout: [B][y(70)][c16(32)][x(70)][8ch]  (chunk-major rows).
#define ROW_ELEMS  (WP_ * CH_)                                // 17,920 per row
#define XP_ELEMS   ((size_t)B_ * WP_ * ROW_ELEMS)             // 20,070,400
#define XP_BYTES   (XP_ELEMS * 2)                             // 40,140,800

#define REPACK_BLOCKS (B_ * (H_ + 6))                         // 1120
#define GENW_BLOCKS   (G_ * G_)                               // 64
#define CONV_BLOCKS   (B_ * (H_ / 2))                         // 512 = 2/CU exactly

static __device__ __forceinline__ unsigned pack_bf16(float a, float b) {
    union { __bf16 h; unsigned short u; } ua, ub;
    ua.h = (__bf16)a; ub.h = (__bf16)b;
    return (unsigned)ua.u | ((unsigned)ub.u << 16);
}

static __device__ __forceinline__ void dma16(const bf16_t* g, bf16_t* l) {
    __builtin_amdgcn_global_load_lds(
        (const __attribute__((address_space(1))) void*)g,
        (__attribute__((address_space(3))) void*)l, 16, 0, 0);
}

// ---------------------------------------------------------------------------
// Fused prep — R0 structure (repack blocks FIRST, gen_w block=(gout,gin)
// LAST, W3 register reuse across 49 taps).  R10's SINGLE-VARIABLE change:
// in gen_w's rep loop, lanes are now cout-innermost (o&31) instead of
// cin-innermost, so each wave's scalar store instruction covers 2x512B
// windows (16 lines) instead of 64 lines at 4KB stride.  Blocking, grid
// order, and all arithmetic unchanged (isolates the store-pattern variable
// that R1/R4 confounded with re-blocking + reordering).
__global__ void prep(const float* __restrict__ x, bf16_t* __restrict__ xp,
                     const float* __restrict__ thetas,
                     const float* __restrict__ W1, const float* __restrict__ b1,
                     const float* __restrict__ W2, const float* __restrict__ b2,
                     const float* __restrict__ W3, const float* __restrict__ b3,
                     bf16_t* __restrict__ w2out) {
    __shared__ float h1s[49][33];
    __shared__ float h2s[49][33];
    __shared__ float masks[49];
    int tid = threadIdx.x;
    if (blockIdx.x < REPACK_BLOCKS) {
        // ---------------- repack path ----------------
        int blk = blockIdx.x;
        int b = blk / (H_ + 6), hy = blk % (H_ + 6);
        const int4 z4 = make_int4(0, 0, 0, 0);
        if (hy >= H_) {
            int idx = hy - H_;
            int y = (idx < 3) ? idx : idx + 64;   // 0,1,2,67,68,69
            bf16_t* dst = xp + ((size_t)(b * WP_) + y) * ROW_ELEMS;
            for (int i = tid; i < ROW_ELEMS / 8; i += 256)
                *reinterpret_cast<int4*>(dst + (size_t)i * 8) = z4;
            return;
        }
        int lane = tid & 63, wv = tid >> 6;
        int r = lane >> 3;          // channel offset in tile -> w offset after T
        int t = lane & 7;           // w-chunk
        size_t orow = ((size_t)(b * WP_) + (hy + 3)) * ROW_ELEMS;
        for (int it = 0; it < 8; ++it) {
            int c0 = wv * 8 + it * 32;
            const float* src = x + ((size_t)(b * CH_ + c0 + r)) * (H_ * W_)
                                 + (size_t)hy * W_ + t * 8;
            float4 f0 = *reinterpret_cast<const float4*>(src);
            float4 f1 = *reinterpret_cast<const float4*>(src + 4);
            int d0 = (int)pack_bf16(f0.x, f0.y);
            int d1 = (int)pack_bf16(f0.z, f0.w);
            int d2 = (int)pack_bf16(f1.x, f1.y);
            int d3 = (int)pack_bf16(f1.z, f1.w);
            int p0, p1, p2, p3;
            p0 = __shfl_xor(d0, 32); p1 = __shfl_xor(d1, 32);
            p2 = __shfl_xor(d2, 32); p3 = __shfl_xor(d3, 32);
            if ((r & 4) == 0) { d2 = p0; d3 = p1; } else { d0 = p2; d1 = p3; }
            p0 = __shfl_xor(d0, 16); p1 = __shfl_xor(d1, 16);
            p2 = __shfl_xor(d2, 16); p3 = __shfl_xor(d3, 16);
            if ((r & 2) == 0) { d1 = p0; d3 = p2; } else { d0 = p1; d2 = p3; }
            p0 = __shfl_xor(d0, 8); p1 = __shfl_xor(d1, 8);
            p2 = __shfl_xor(d2, 8); p3 = __shfl_xor(d3, 8);
            if ((r & 1) == 0) {
                d0 = (d0 & 0xFFFF) | (p0 << 16);
                d1 = (d1 & 0xFFFF) | (p1 << 16);
                d2 = (d2 & 0xFFFF) | (p2 << 16);
                d3 = (d3 & 0xFFFF) | (p3 << 16);
            } else {
                d0 = (d0 & 0xFFFF0000) | ((unsigned)p0 >> 16);
                d1 = (d1 & 0xFFFF0000) | ((unsigned)p1 >> 16);
                d2 = (d2 & 0xFFFF0000) | ((unsigned)p2 >> 16);
                d3 = (d3 & 0xFFFF0000) | ((unsigned)p3 >> 16);
            }
            int xpos = t * 8 + r + 3;
            int c16 = c0 >> 3;
            int4 v = make_int4(d0, d1, d2, d3);
            // chunk-major: wave's 64 stores cover one contiguous 1024B run
            *reinterpret_cast<int4*>(xp + orow + ((size_t)c16 * WP_ + xpos) * 8) = v;
        }
        if (tid < 192) {   // zero w-border cols {0,1,2,67,68,69} in every chunk
            int col = tid >> 5, cg = tid & 31;
            int xx = (col < 3) ? col : col + 64;
            *reinterpret_cast<int4*>(xp + orow + ((size_t)cg * WP_ + xx) * 8) = z4;
        }
        return;
    }
    // ---------------- gen_w path: block = (gout, gin) ----------------
    int blk = blockIdx.x - REPACK_BLOCKS;
    int gin = blk & 7, gout = blk >> 3;
    const float TWO_PI = 6.283185307179586f;
    const float PI_F   = 3.14159265358979323846f;
    float th_o = thetas[gout], th_i = thetas[gin];
    float d = fmodf(th_i - th_o, TWO_PI);
    if (d < 0.0f) d += TWO_PI;
    float ag = d / PI_F - 1.0f;
    float ct = cosf(-th_o), st = sinf(-th_o);

    if (tid < 196) {
        int p = tid >> 2, q = tid & 3;       // tap, j-octet
        int ky = p / 7, kx = p % 7;
        float yy = (float)(ky - 3) / 3.0f;
        float xx = (float)(kx - 3) / 3.0f;
        float r0 = ct * yy - st * xx;
        float r1 = st * yy + ct * xx;
        if (q == 0)   // radius-1 points INCLUDED (fp32 ref); next r^2 = 10/9
            masks[p] = (r0 * r0 + r1 * r1 <= 1.00001f) ? 1.0f : 0.0f;
        #pragma unroll
        for (int jo = 0; jo < 8; ++jo) {
            int j = q * 8 + jo;
            float a = r0 * W1[j] + r1 * W1[32 + j] + ag * W1[64 + j] + b1[j];
            h1s[p][j] = __sinf(10.0f * a);
        }
    }
    __syncthreads();
    if (tid < 196) {
        int p = tid >> 2, q = tid & 3;
        #pragma unroll
        for (int jo = 0; jo < 8; ++jo) {
            int j = q * 8 + jo;
            float a = b2[j];
            #pragma unroll
            for (int i = 0; i < HID_; ++i) a += h1s[p][i] * W2[i * HID_ + j];
            h2s[p][j] = __sinf(10.0f * a);
        }
    }
    __syncthreads();
    for (int rep = 0; rep < 4; ++rep) {
        int o = rep * 256 + tid;
        int cout = o & 31, cin = o >> 5;     // R10: cout innermost -> wave stores
        int col = cout * 32 + cin;           //      land in 2x512B windows
        float w3c[HID_];
        #pragma unroll
        for (int i = 0; i < HID_; ++i) w3c[i] = W3[i * 1024 + col];
        float bb = b3[col];
        int k = cin * G_ + gin;
        int n = gout * COUT_ + cout;
        int kc = k >> 5, hi = (k >> 3) & 3, jj = k & 7;
        bf16_t* dst = w2out + (((size_t)kc * 4 + hi) * 256 + n) * 8 + jj;
        for (int p = 0; p < 49; ++p) {
            float a = bb;
            #pragma unroll
            for (int i = 0; i < HID_; ++i) a += h2s[p][i] * w3c[i];
            a *= masks[p];
            dst[(size_t)p * (8 * 4 * 256 * 8)] = (bf16_t)a;
        }
    }
}

// ---------------------------------------------------------------------------
// Conv — EXACT R5 version (best measured: 265us, MfmaUtil 74.4, reproduced
// across 10+ dispatches).  R6-R9's 32x32x16 family (1-deep, 2-deep, fused
// steps) all landed 312-335us — that direction is empirically dead here.
// Implicit GEMM, block = (b, h-pair), wave = 64-wide N-strip over full
// M=128, acc[8][4] on 16x16x32 MFMA.  kc-octet hand-unrolled (compile-time
// offsets, uniform SGPR B base), s_setprio around each 32-MFMA cluster,
// 1-step-ahead cur/nxt rotation for both operand streams.
#define CONV_STEP(AC, AN, BC, BN, PC, PB, AOF)                                \
  do {                                                                        \
    _Pragma("unroll")                                                         \
    for (int nt = 0; nt < 4; ++nt)                                            \
      BN[nt] = *reinterpret_cast<const bf16x8*>(                              \
          (PB) + wlane_off + (PC) * 8192 + nt * 128);                         \
    _Pragma("unroll")                                                         \
    for (int mt = 0; mt < 4; ++mt) {                                          \
      AN[mt]     = *reinterpret_cast<const bf16x8*>(                          \
          aA + ((PC) * 4 * WP_ + mt * 16) * 8 + (AOF));                       \
      AN[mt + 4] = *reinterpret_cast<const bf16x8*>(                          \
          aB + ((PC) * 4 * WP_ + mt * 16) * 8 + (AOF));                       \
    }                                                                         \
    __builtin_amdgcn_s_setprio(1);                                            \
    _Pragma("unroll")                                                         \
    for (int mt = 0; mt < 8; ++mt)                                            \
      _Pragma("unroll")                                                       \
      for (int nt = 0; nt < 4; ++nt)                                          \
        acc[mt][nt] = __builtin_amdgcn_mfma_f32_16x16x32_bf16(                \
            AC[mt], BC[nt], acc[mt][nt], 0, 0, 0);                            \
    __builtin_amdgcn_s_setprio(0);                                            \
  } while (0)

__launch_bounds__(256, 2)
__global__ void conv_mfma(const bf16_t* __restrict__ xp,
                          const bf16_t* __restrict__ w2,
                          const float* __restrict__ bias,
                          float* __restrict__ out) {
    __shared__ __align__(16) bf16_t lds[2][ROW_ELEMS];   // 71,680 B
    int blk = blockIdx.x;             // b*32 + hpair
    int b = blk >> 5, h0 = (blk & 31) << 1;
    int tid = threadIdx.x;
    int ns = tid >> 6, lane = tid & 63;
    int lm = lane & 15, lq = lane >> 4;
    int wlane_off = lq * 2048 + (ns * 64 + lm) * 8;   // divergent, loop-invariant

    f32x4 acc[8][4];
    #pragma unroll
    for (int i = 0; i < 8; ++i)
        #pragma unroll
        for (int j = 0; j < 4; ++j) {
            f32x4 z = {0.0f, 0.0f, 0.0f, 0.0f};
            acc[i][j] = z;
        }

    const bf16_t* rows = xp + (((size_t)(b * WP_) + h0)) * ROW_ELEMS;
    // init: stage rows h0 (slot0) and h0+1 (slot1): 70 chunks of 1KB, linear
    for (int c = ns; c < 70; c += 4)
        dma16(rows + (size_t)c * 512 + lane * 8, &lds[0][0] + c * 512);

    // B prologue: prefetch step (tap 0, kc 0)
    bf16x8 bcur[4], bnxt[4];
    #pragma unroll
    for (int nt = 0; nt < 4; ++nt)
        bcur[nt] = *reinterpret_cast<const bf16x8*>(w2 + wlane_off + nt * 128);
    __syncthreads();   // drains init DMA (vmcnt 0) before LDS reads

    for (int ky = 0; ky < KS_; ++ky) {
        const bf16_t* slotA = &lds[ky & 1][0];        // image row h0+ky   (mt 0-3)
        const bf16_t* slotB = &lds[(ky + 1) & 1][0];  // image row h0+ky+1 (mt 4-7)
        // A(0) prologue for this ky (kx=0, kc=0)
        bf16x8 acur[8], anxt[8];
        #pragma unroll
        for (int mt = 0; mt < 4; ++mt) {
            int xr = (lq * WP_ + lm) * 8 + mt * 128;
            acur[mt]     = *reinterpret_cast<const bf16x8*>(&slotA[xr]);
            acur[mt + 4] = *reinterpret_cast<const bf16x8*>(&slotB[xr]);
        }
        #pragma unroll 1
        for (int kx = 0; kx < 7; ++kx) {
            const bf16_t* wkx = w2 + (size_t)(ky * 7 + kx) * 65536;  // uniform
            const bf16_t* wnx = (ky == 6 && kx == 6) ? wkx : wkx + 65536;
            const bf16_t* aA = slotA + (lq * WP_ + lm + kx) * 8;
            const bf16_t* aB = slotB + (lq * WP_ + lm + kx) * 8;
            CONV_STEP(acur, anxt, bcur, bnxt, 1, wkx, 0);
            CONV_STEP(anxt, acur, bnxt, bcur, 2, wkx, 0);
            CONV_STEP(acur, anxt, bcur, bnxt, 3, wkx, 0);
            CONV_STEP(anxt, acur, bnxt, bcur, 4, wkx, 0);
            CONV_STEP(acur, anxt, bcur, bnxt, 5, wkx, 0);
            CONV_STEP(anxt, acur, bnxt, bcur, 6, wkx, 0);
            CONV_STEP(acur, anxt, bcur, bnxt, 7, wkx, 0);
            CONV_STEP(anxt, acur, bnxt, bcur, 0, wnx, 8);  // next kx / next ky B(0); A dead at kx=6
        }
        if (ky < KS_ - 1) {
            __syncthreads();   // all waves done with row h0+ky (slot ky&1)
            bf16_t* dstslot = &lds[ky & 1][0];
            const bf16_t* src = rows + (size_t)(ky + 2) * ROW_ELEMS;
            for (int c = ns; c < 35; c += 4)
                dma16(src + (size_t)c * 512 + lane * 8, dstslot + c * 512);
            __syncthreads();   // drain DMA
        }
    }

    // epilogue: D row = lq*4 + reg (w offset), col = lm (n offset)
    #pragma unroll
    for (int mt = 0; mt < 8; ++mt) {
        int h = h0 + (mt >> 2);
        int wq = (mt & 3) * 16 + lq * 4;
        #pragma unroll
        for (int nt = 0; nt < 4; ++nt) {
            int n = ns * 64 + nt * 16 + lm;
            int gout = n >> 5, cout = n & 31;
            float bv = bias[cout];
            f32x4 v = acc[mt][nt];
            v[0] += bv; v[1] += bv; v[2] += bv; v[3] += bv;
            float* po = out + (((size_t)(b * COUT_ + cout) * G_ + gout) * (H_ * W_)
                               + h * W_ + wq);
            *reinterpret_cast<f32x4*>(po) = v;
        }
    }
}

// ---------------------------------------------------------------------------
extern "C" void kernel_launch(void* const* d_in, const int* in_sizes, int n_in,
                              void* d_out, int out_size, void* d_ws, size_t ws_size,
                              hipStream_t stream) {
    const float* x      = (const float*)d_in[0];
    const float* thetas = (const float*)d_in[1];
    const float* W1     = (const float*)d_in[2];
    const float* b1     = (const float*)d_in[3];
    const float* W2     = (const float*)d_in[4];
    const float* b2     = (const float*)d_in[5];
    const float* W3     = (const float*)d_in[6];
    const float* b3     = (const float*)d_in[7];
    const float* bias   = (const float*)d_in[8];
    float* out = (float*)d_out;

    bf16_t* xp = (bf16_t*)d_ws;
    bf16_t* w2 = (bf16_t*)((char*)d_ws + XP_BYTES);

    hipLaunchKernelGGL(prep, dim3(REPACK_BLOCKS + GENW_BLOCKS), dim3(256), 0, stream,
                       x, xp, thetas, W1, b1, W2, b2, W3, b3, w2);
    hipLaunchKernelGGL(conv_mfma, dim3(CONV_BLOCKS), dim3(256), 0, stream,
                       xp, w2, bias, out);
}

// Round 11
// 463.564 us; speedup vs baseline: 1.0910x; 1.0330x over previous
//
#include <hip/hip_runtime.h>
#include <math.h>

typedef __bf16 bf16_t;
typedef __bf16 bf16x8 __attribute__((ext_vector_type(8)));
typedef float  f32x4  __attribute__((ext_vector_type(4)));

#define B_    16
#define CIN_  32
#define COUT_ 32
#define G_    8
#define CH_   256      // Cin*Gin = K channels per tap
#define H_    64
#define W_    64
#define HID_  32
#define KS_   7
#define PAD_  3
#define WP_   70       // W + 2*PAD

// LDS row layout (chunk-major, identical to the old xp rows):
//   [c16(32)][x(70)][8ch], c16 = channel-octet = cin, element = gin.
#define ROW_ELEMS  (WP_ * CH_)                                // 17,920 per row

#define GENW_BLOCKS   (G_ * G_)                               // 64
#define CONV_BLOCKS   (B_ * (H_ / 2))                         // 512 = 2/CU exactly

static __device__ __forceinline__ unsigned pack_bf16(float a, float b) {
    union { __bf16 h; unsigned short u; } ua, ub;
    ua.h = (__bf16)a; ub.h = (__bf16)b;
    return (unsigned)ua.u | ((unsigned)ub.u << 16);
}

// ---------------------------------------------------------------------------
// gen_w — EXACT R0 gen_w path as a standalone kernel (64 blocks = (gout,gin),
// W3 register reuse across all 49 taps, cin-innermost lanes).  Three rewrites
// (R1/R4/R10) all regressed; FROZEN.
__global__ void gen_w(const float* __restrict__ thetas,
                      const float* __restrict__ W1, const float* __restrict__ b1,
                      const float* __restrict__ W2, const float* __restrict__ b2,
                      const float* __restrict__ W3, const float* __restrict__ b3,
                      bf16_t* __restrict__ w2out) {
    __shared__ float h1s[49][33];
    __shared__ float h2s[49][33];
    __shared__ float masks[49];
    int tid = threadIdx.x;
    int blk = blockIdx.x;
    int gin = blk & 7, gout = blk >> 3;
    const float TWO_PI = 6.283185307179586f;
    const float PI_F   = 3.14159265358979323846f;
    float th_o = thetas[gout], th_i = thetas[gin];
    float d = fmodf(th_i - th_o, TWO_PI);
    if (d < 0.0f) d += TWO_PI;
    float ag = d / PI_F - 1.0f;
    float ct = cosf(-th_o), st = sinf(-th_o);

    if (tid < 196) {
        int p = tid >> 2, q = tid & 3;       // tap, j-octet
        int ky = p / 7, kx = p % 7;
        float yy = (float)(ky - 3) / 3.0f;
        float xx = (float)(kx - 3) / 3.0f;
        float r0 = ct * yy - st * xx;
        float r1 = st * yy + ct * xx;
        if (q == 0)   // radius-1 points INCLUDED (fp32 ref)
            masks[p] = (r0 * r0 + r1 * r1 <= 1.00001f) ? 1.0f : 0.0f;
        #pragma unroll
        for (int jo = 0; jo < 8; ++jo) {
            int j = q * 8 + jo;
            float a = r0 * W1[j] + r1 * W1[32 + j] + ag * W1[64 + j] + b1[j];
            h1s[p][j] = __sinf(10.0f * a);
        }
    }
    __syncthreads();
    if (tid < 196) {
        int p = tid >> 2, q = tid & 3;
        #pragma unroll
        for (int jo = 0; jo < 8; ++jo) {
            int j = q * 8 + jo;
            float a = b2[j];
            #pragma unroll
            for (int i = 0; i < HID_; ++i) a += h1s[p][i] * W2[i * HID_ + j];
            h2s[p][j] = __sinf(10.0f * a);
        }
    }
    __syncthreads();
    for (int rep = 0; rep < 4; ++rep) {
        int o = rep * 256 + tid;             // cout*32 + cin
        float w3c[HID_];
        #pragma unroll
        for (int i = 0; i < HID_; ++i) w3c[i] = W3[i * 1024 + o];
        float bb = b3[o];
        int cout = o >> 5, cin = o & 31;
        int k = cin * G_ + gin;
        int n = gout * COUT_ + cout;
        int kc = k >> 5, hi = (k >> 3) & 3, jj = k & 7;
        bf16_t* dst = w2out + (((size_t)kc * 4 + hi) * 256 + n) * 8 + jj;
        for (int p = 0; p < 49; ++p) {
            float a = bb;
            #pragma unroll
            for (int i = 0; i < HID_; ++i) a += h2s[p][i] * w3c[i];
            a *= masks[p];
            dst[(size_t)p * (8 * 4 * 256 * 8)] = (bf16_t)a;
        }
    }
}

// ---------------------------------------------------------------------------
// stage_row: transpose one padded image row of x directly into an LDS slot,
// using the HW-verified repack wave-shfl 8x8 network (R0 prep, destination
// changed from global xp to LDS).  slot[c16][x][e] = bf16 x[b, c16*8+e, y, x-3],
// zero for x<3, x>=67, and for padded rows y<3 / y>66 (whole slot zeroed).
static __device__ __forceinline__ void stage_row(bf16_t* slot,
                                                 const float* __restrict__ x,
                                                 int b, int ypad, int tid) {
    const int4 z4 = make_int4(0, 0, 0, 0);
    if (ypad < 3 || ypad > 66) {
        for (int i = tid; i < ROW_ELEMS / 8; i += 256)
            *reinterpret_cast<int4*>(slot + (size_t)i * 8) = z4;
        return;
    }
    int hy = ypad - 3;
    int lane = tid & 63, wv = tid >> 6;
    int r = lane >> 3;          // channel offset in tile -> w offset after T
    int t = lane & 7;           // w-chunk
    for (int it = 0; it < 8; ++it) {
        int c0 = wv * 8 + it * 32;
        const float* src = x + ((size_t)(b * CH_ + c0 + r)) * (H_ * W_)
                             + (size_t)hy * W_ + t * 8;
        float4 f0 = *reinterpret_cast<const float4*>(src);
        float4 f1 = *reinterpret_cast<const float4*>(src + 4);
        int d0 = (int)pack_bf16(f0.x, f0.y);
        int d1 = (int)pack_bf16(f0.z, f0.w);
        int d2 = (int)pack_bf16(f1.x, f1.y);
        int d3 = (int)pack_bf16(f1.z, f1.w);
        int p0, p1, p2, p3;
        p0 = __shfl_xor(d0, 32); p1 = __shfl_xor(d1, 32);
        p2 = __shfl_xor(d2, 32); p3 = __shfl_xor(d3, 32);
        if ((r & 4) == 0) { d2 = p0; d3 = p1; } else { d0 = p2; d1 = p3; }
        p0 = __shfl_xor(d0, 16); p1 = __shfl_xor(d1, 16);
        p2 = __shfl_xor(d2, 16); p3 = __shfl_xor(d3, 16);
        if ((r & 2) == 0) { d1 = p0; d3 = p2; } else { d0 = p1; d2 = p3; }
        p0 = __shfl_xor(d0, 8); p1 = __shfl_xor(d1, 8);
        p2 = __shfl_xor(d2, 8); p3 = __shfl_xor(d3, 8);
        if ((r & 1) == 0) {
            d0 = (d0 & 0xFFFF) | (p0 << 16);
            d1 = (d1 & 0xFFFF) | (p1 << 16);
            d2 = (d2 & 0xFFFF) | (p2 << 16);
            d3 = (d3 & 0xFFFF) | (p3 << 16);
        } else {
            d0 = (d0 & 0xFFFF0000) | ((unsigned)p0 >> 16);
            d1 = (d1 & 0xFFFF0000) | ((unsigned)p1 >> 16);
            d2 = (d2 & 0xFFFF0000) | ((unsigned)p2 >> 16);
            d3 = (d3 & 0xFFFF0000) | ((unsigned)p3 >> 16);
        }
        int xpos = t * 8 + r + 3;
        int c16 = c0 >> 3;
        *reinterpret_cast<int4*>(slot + ((size_t)c16 * WP_ + xpos) * 8)
            = make_int4(d0, d1, d2, d3);
    }
    if (tid < 192) {   // zero w-border cols {0,1,2,67,68,69} in every chunk
        int col = tid >> 5, cg = tid & 31;
        int xx = (col < 3) ? col : col + 64;
        *reinterpret_cast<int4*>(slot + ((size_t)cg * WP_ + xx) * 8) = z4;
    }
}

// ---------------------------------------------------------------------------
// Conv — R5's verified 16x16x32 pipeline (best: 265-275us, MfmaUtil ~74),
// with R11's change: the xp intermediate is GONE.  Each block transposes its
// own 8 rows of x into the 2-slot LDS ring via stage_row (the repack shfl
// network inlined), inside the same barrier windows that previously held the
// global_load_lds DMA.  Eliminates the repack kernel, the 40MB xp write and
// the 143MB xp read — the whole prep+gap except gen_w.
#define CONV_STEP(AC, AN, BC, BN, PC, PB, AOF)                                \
  do {                                                                        \
    _Pragma("unroll")                                                         \
    for (int nt = 0; nt < 4; ++nt)                                            \
      BN[nt] = *reinterpret_cast<const bf16x8*>(                              \
          (PB) + wlane_off + (PC) * 8192 + nt * 128);                         \
    _Pragma("unroll")                                                         \
    for (int mt = 0; mt < 4; ++mt) {                                          \
      AN[mt]     = *reinterpret_cast<const bf16x8*>(                          \
          aA + ((PC) * 4 * WP_ + mt * 16) * 8 + (AOF));                       \
      AN[mt + 4] = *reinterpret_cast<const bf16x8*>(                          \
          aB + ((PC) * 4 * WP_ + mt * 16) * 8 + (AOF));                       \
    }                                                                         \
    __builtin_amdgcn_s_setprio(1);                                            \
    _Pragma("unroll")                                                         \
    for (int mt = 0; mt < 8; ++mt)                                            \
      _Pragma("unroll")                                                       \
      for (int nt = 0; nt < 4; ++nt)                                          \
        acc[mt][nt] = __builtin_amdgcn_mfma_f32_16x16x32_bf16(                \
            AC[mt], BC[nt], acc[mt][nt], 0, 0, 0);                            \
    __builtin_amdgcn_s_setprio(0);                                            \
  } while (0)

__launch_bounds__(256, 2)
__global__ void conv_mfma(const float* __restrict__ x,
                          const bf16_t* __restrict__ w2,
                          const float* __restrict__ bias,
                          float* __restrict__ out) {
    __shared__ __align__(16) bf16_t lds[2][ROW_ELEMS];   // 71,680 B
    int blk = blockIdx.x;             // b*32 + hpair
    int b = blk >> 5, h0 = (blk & 31) << 1;
    int tid = threadIdx.x;
    int ns = tid >> 6, lane = tid & 63;
    int lm = lane & 15, lq = lane >> 4;
    int wlane_off = lq * 2048 + (ns * 64 + lm) * 8;   // divergent, loop-invariant

    f32x4 acc[8][4];
    #pragma unroll
    for (int i = 0; i < 8; ++i)
        #pragma unroll
        for (int j = 0; j < 4; ++j) {
            f32x4 z = {0.0f, 0.0f, 0.0f, 0.0f};
            acc[i][j] = z;
        }

    // init: transpose padded rows h0 -> slot0, h0+1 -> slot1
    stage_row(&lds[0][0], x, b, h0,     tid);
    stage_row(&lds[1][0], x, b, h0 + 1, tid);

    // B prologue: prefetch step (tap 0, kc 0)
    bf16x8 bcur[4], bnxt[4];
    #pragma unroll
    for (int nt = 0; nt < 4; ++nt)
        bcur[nt] = *reinterpret_cast<const bf16x8*>(w2 + wlane_off + nt * 128);
    __syncthreads();   // staging writes visible before LDS reads

    for (int ky = 0; ky < KS_; ++ky) {
        const bf16_t* slotA = &lds[ky & 1][0];        // padded row h0+ky   (mt 0-3)
        const bf16_t* slotB = &lds[(ky + 1) & 1][0];  // padded row h0+ky+1 (mt 4-7)
        // A(0) prologue for this ky (kx=0, kc=0)
        bf16x8 acur[8], anxt[8];
        #pragma unroll
        for (int mt = 0; mt < 4; ++mt) {
            int xr = (lq * WP_ + lm) * 8 + mt * 128;
            acur[mt]     = *reinterpret_cast<const bf16x8*>(&slotA[xr]);
            acur[mt + 4] = *reinterpret_cast<const bf16x8*>(&slotB[xr]);
        }
        #pragma unroll 1
        for (int kx = 0; kx < 7; ++kx) {
            const bf16_t* wkx = w2 + (size_t)(ky * 7 + kx) * 65536;  // uniform
            const bf16_t* wnx = (ky == 6 && kx == 6) ? wkx : wkx + 65536;
            const bf16_t* aA = slotA + (lq * WP_ + lm + kx) * 8;
            const bf16_t* aB = slotB + (lq * WP_ + lm + kx) * 8;
            CONV_STEP(acur, anxt, bcur, bnxt, 1, wkx, 0);
            CONV_STEP(anxt, acur, bnxt, bcur, 2, wkx, 0);
            CONV_STEP(acur, anxt, bcur, bnxt, 3, wkx, 0);
            CONV_STEP(anxt, acur, bnxt, bcur, 4, wkx, 0);
            CONV_STEP(acur, anxt, bcur, bnxt, 5, wkx, 0);
            CONV_STEP(anxt, acur, bnxt, bcur, 6, wkx, 0);
            CONV_STEP(acur, anxt, bcur, bnxt, 7, wkx, 0);
            CONV_STEP(anxt, acur, bnxt, bcur, 0, wnx, 8);  // next kx/ky B(0); A dead at kx=6
        }
        if (ky < KS_ - 1) {
            __syncthreads();   // all waves done with slot ky&1
            stage_row(&lds[ky & 1][0], x, b, h0 + ky + 2, tid);
            __syncthreads();   // staging writes visible
        }
    }

    // epilogue: D row = lq*4 + reg (w offset), col = lm (n offset)
    #pragma unroll
    for (int mt = 0; mt < 8; ++mt) {
        int h = h0 + (mt >> 2);
        int wq = (mt & 3) * 16 + lq * 4;
        #pragma unroll
        for (int nt = 0; nt < 4; ++nt) {
            int n = ns * 64 + nt * 16 + lm;
            int gout = n >> 5, cout = n & 31;
            float bv = bias[cout];
            f32x4 v = acc[mt][nt];
            v[0] += bv; v[1] += bv; v[2] += bv; v[3] += bv;
            float* po = out + (((size_t)(b * COUT_ + cout) * G_ + gout) * (H_ * W_)
                               + h * W_ + wq);
            *reinterpret_cast<f32x4*>(po) = v;
        }
    }
}

// ---------------------------------------------------------------------------
extern "C" void kernel_launch(void* const* d_in, const int* in_sizes, int n_in,
                              void* d_out, int out_size, void* d_ws, size_t ws_size,
                              hipStream_t stream) {
    const float* x      = (const float*)d_in[0];
    const float* thetas = (const float*)d_in[1];
    const float* W1     = (const float*)d_in[2];
    const float* b1     = (const float*)d_in[3];
    const float* W2     = (const float*)d_in[4];
    const float* b2     = (const float*)d_in[5];
    const float* W3     = (const float*)d_in[6];
    const float* b3     = (const float*)d_in[7];
    const float* bias   = (const float*)d_in[8];
    float* out = (float*)d_out;

    bf16_t* w2 = (bf16_t*)d_ws;    // 6.4 MB; xp intermediate eliminated

    hipLaunchKernelGGL(gen_w, dim3(GENW_BLOCKS), dim3(256), 0, stream,
                       thetas, W1, b1, W2, b2, W3, b3, w2);
    hipLaunchKernelGGL(conv_mfma, dim3(CONV_BLOCKS), dim3(256), 0, stream,
                       x, w2, bias, out);
}